// Round 4
// baseline (1834.540 us; speedup 1.0000x reference)
//
#include <hip/hip_runtime.h>
#include <hip/hip_bf16.h>
#include <stdint.h>

// Problem constants
#define NN   16384   // nodes
#define FI   128     // in feats
#define FH   128     // hidden
#define FO   64      // out feats

// Kernel-2 decomposition: one wave owns 16 adj rows x all 128 output cols,
// sweeping half the K range (k-split 2).  2048 waves total, 512 blocks.
#define KS    32               // K per step (one MFMA K)
#define KHALF (NN / 2)         // 8192
#define NS    (KHALF / KS)     // 256 steps per wave
#define NPART 1024             // colsum partial rows (4 waves x 256 row-blocks)

typedef float f32x4 __attribute__((ext_vector_type(4)));
typedef short s16x8 __attribute__((ext_vector_type(8)));

__device__ __forceinline__ unsigned short f2bf(float f) {
    union { float f; unsigned u; } v; v.f = f;
    unsigned u = v.u;
    return (unsigned short)((u + 0x7FFFu + ((u >> 16) & 1u)) >> 16);  // RNE
}

// ---------------------------------------------------------------------------
// Kernel 1: S1T[n][k] = sum_f x[k][f] * W1[f][n], stored bf16 TRANSPOSED
// (n-major) so kernel 2 can read B-fragments with contiguous 16 B loads.
// ---------------------------------------------------------------------------
__global__ __launch_bounds__(256) void k1_s1t(const float* __restrict__ x,
                                              const float* __restrict__ W1,
                                              unsigned short* __restrict__ S1T) {
    __shared__ float w1s[FI][FH];     // [f][n], 64 KB, reads are wave-uniform (broadcast)
    __shared__ float xs[64][132];     // 64 k-rows, pad 132 -> uniform 8-way b128 (optimal)

    const int t  = threadIdx.x;
    const int b  = blockIdx.x;        // 256 blocks
    const int k0 = b * 64;

    float* wflat = &w1s[0][0];
    for (int i = t; i < FI * FH; i += 256) wflat[i] = W1[i];

    #pragma unroll
    for (int s = 0; s < 8; ++s) {
        int idx = t + 256 * s;              // 2048 float4 chunks
        int r   = idx >> 5;                 // 0..63
        int f4  = idx & 31;
        f32x4 vv = *(const f32x4*)(x + (size_t)(k0 + r) * FI + f4 * 4);
        *(f32x4*)(&xs[r][f4 * 4]) = vv;
    }
    __syncthreads();

    const int w = t >> 6;                   // wave = n-group (32 cols)
    const int l = t & 63;                   // lane = k-row

    float acc[32];
    #pragma unroll
    for (int j = 0; j < 32; ++j) acc[j] = 0.f;

    for (int f4 = 0; f4 < 32; ++f4) {
        f32x4 xv = *(const f32x4*)(&xs[l][f4 * 4]);
        #pragma unroll
        for (int e = 0; e < 4; ++e) {
            const int f = f4 * 4 + e;
            #pragma unroll
            for (int cth = 0; cth < 8; ++cth) {
                f32x4 wv = *(const f32x4*)(&w1s[f][w * 32 + cth * 4]);  // broadcast
                acc[cth * 4 + 0] += xv[e] * wv[0];
                acc[cth * 4 + 1] += xv[e] * wv[1];
                acc[cth * 4 + 2] += xv[e] * wv[2];
                acc[cth * 4 + 3] += xv[e] * wv[3];
            }
        }
    }

    const int k = k0 + l;
    #pragma unroll
    for (int j = 0; j < 32; ++j) {
        const int n = w * 32 + j;
        S1T[(size_t)n * NN + k] = f2bf(acc[j]);   // lanes -> consecutive k, coalesced
    }
}

// ---------------------------------------------------------------------------
// Kernel 2 (v4): T = adj @ S1 — BARRIER-FREE, LDS-FREE.
//
// Each wave owns 16 adj rows x 128 output cols and privately sweeps half of
// K.  adj is fetched exactly once device-wide (no A-sharing needed -> no
// LDS, no barriers, no drain points); S1T (4 MiB) is re-read from L2
// (~50 B/cyc/CU < the 56 B/cyc L2 ceiling).  Latency hidden by 8 waves/CU +
// register double-buffer (loads for step s+1 issued before computing step s;
// compiler emits counted vmcnt).  Colsum partials: 4-level __shfl_xor tree
// over the 16 m-lanes, lanes m==0 store 32 B -> cpart[1024][NN].
// K-split halves write disjoint Tpart[2] slabs; k3 sums them.
// ---------------------------------------------------------------------------
__global__ __launch_bounds__(256, 2) void k2_agg(const float* __restrict__ adj,
                                                 const unsigned short* __restrict__ S1T,
                                                 float* __restrict__ Tpart,
                                                 float* __restrict__ cpart) {
    const int t    = threadIdx.x;
    const int w    = t >> 6;
    const int l    = t & 63;
    const int m    = l & 15;        // MFMA A row within wave tile
    const int quad = l >> 4;        // MFMA k-subgroup

    const int rb = blockIdx.x >> 1;           // row-block 0..255
    const int kh = blockIdx.x & 1;            // k-half
    const long r0 = (long)rb * 64 + w * 16;   // this wave's first adj row
    const int  k0 = kh * KHALF;

    f32x4 acc[8];
    #pragma unroll
    for (int nt = 0; nt < 8; ++nt) acc[nt] = (f32x4){0.f, 0.f, 0.f, 0.f};

    const float* aptr = adj + (size_t)(r0 + m) * NN + k0 + quad * 8;
    float* cp = cpart + (size_t)(rb * 4 + w) * NN + k0 + quad * 8;

    // double-buffered register sets (named -> stay in VGPRs)
    f32x4 aC0, aC1, aN0, aN1;
    s16x8 bC[8], bN[8];

#define LOADA(A0, A1, S) do {                                                     \
    const float* p_ = aptr + (size_t)(S) * KS;                                    \
    A0 = *(const f32x4*)p_;                                                       \
    A1 = *(const f32x4*)(p_ + 4);                                                 \
} while (0)

#define LOADB(B, S) do {                                                          \
    const size_t ko_ = (size_t)k0 + (size_t)(S) * KS + quad * 8;                  \
    _Pragma("unroll")                                                             \
    for (int nt_ = 0; nt_ < 8; ++nt_)                                             \
        B[nt_] = *(const s16x8*)(S1T + (size_t)(nt_ * 16 + m) * NN + ko_);        \
} while (0)

// colsum over the 16 m-lanes (xor 1,2,4,8 stays within the quad group),
// then lanes m==0 store 32 B (cols quad*8 .. quad*8+7 of this step)
#define CSUM(A0, A1, S) do {                                                      \
    f32x4 p0_ = A0, p1_ = A1;                                                     \
    _Pragma("unroll")                                                             \
    for (int mk_ = 1; mk_ < 16; mk_ <<= 1) {                                      \
        _Pragma("unroll")                                                         \
        for (int e_ = 0; e_ < 4; ++e_) {                                          \
            p0_[e_] += __shfl_xor(p0_[e_], mk_);                                  \
            p1_[e_] += __shfl_xor(p1_[e_], mk_);                                  \
        }                                                                         \
    }                                                                             \
    if (m == 0) {                                                                 \
        float* q_ = cp + (size_t)(S) * KS;                                        \
        *(f32x4*)q_       = p0_;                                                  \
        *(f32x4*)(q_ + 4) = p1_;                                                  \
    }                                                                             \
} while (0)

#define STEP(A0, A1, B) do {                                                      \
    s16x8 abf_;                                                                   \
    _Pragma("unroll")                                                             \
    for (int e_ = 0; e_ < 4; ++e_) {                                              \
        abf_[e_]     = (short)f2bf(A0[e_]);                                       \
        abf_[e_ + 4] = (short)f2bf(A1[e_]);                                       \
    }                                                                             \
    _Pragma("unroll")                                                             \
    for (int nt_ = 0; nt_ < 8; ++nt_)                                             \
        acc[nt_] = __builtin_amdgcn_mfma_f32_16x16x32_bf16(                       \
            abf_, B[nt_], acc[nt_], 0, 0, 0);                                     \
} while (0)

    LOADA(aC0, aC1, 0);
    LOADB(bC, 0);

    for (int s = 0; s < NS; s += 2) {
        // issue step s+1 loads, compute step s  (s+1 <= 255 always in range)
        LOADA(aN0, aN1, s + 1);
        LOADB(bN, s + 1);
        CSUM(aC0, aC1, s);
        STEP(aC0, aC1, bC);

        // issue step s+2 loads, compute step s+1
        if (s + 2 < NS) {
            LOADA(aC0, aC1, s + 2);
            LOADB(bC, s + 2);
        }
        CSUM(aN0, aN1, s + 1);
        STEP(aN0, aN1, bN);
    }

#undef LOADA
#undef LOADB
#undef CSUM
#undef STEP

    // epilogue: C/D layout col=lane&15, row=quad*4+reg; write this k-half's slab
    float* Tp = Tpart + (size_t)kh * NN * FH;
    #pragma unroll
    for (int nt = 0; nt < 8; ++nt) {
        const int col = nt * 16 + m;
        #pragma unroll
        for (int r = 0; r < 4; ++r) {
            const long row = r0 + quad * 4 + r;
            Tp[row * FH + col] = acc[nt][r];
        }
    }
}

// ---------------------------------------------------------------------------
// Kernel 3: finish colsum c[k] = sum_p cpart[p][k] (1024 partials, coalesced),
// then v[m] = sum_k c[k] * relu(Tpart0[k][m] + Tpart1[k][m] + b1[m])
// ---------------------------------------------------------------------------
__global__ __launch_bounds__(256) void k3_v(const float* __restrict__ Tpart,
                                            const float* __restrict__ cpart,
                                            const float* __restrict__ b1,
                                            float* __restrict__ v) {
    __shared__ float vp[FH];
    __shared__ float cw[4][64];
    __shared__ float cloc[64];

    const int t = threadIdx.x;
    const int b = blockIdx.x;      // 256 blocks x 64 rows
    const int w = t >> 6;
    const int l = t & 63;

    // 1024-way partial reduction for this block's 64 k-rows.
    // wave w sums rows {w, w+4, w+8, ...}; lanes -> consecutive k (coalesced).
    float s = 0.f;
    #pragma unroll 8
    for (int i = 0; i < NPART / 4; ++i)
        s += cpart[(size_t)(w + 4 * i) * NN + b * 64 + l];
    cw[w][l] = s;
    if (t < FH) vp[t] = 0.f;
    __syncthreads();
    if (t < 64) cloc[t] = cw[0][t] + cw[1][t] + cw[2][t] + cw[3][t];
    __syncthreads();

    const int kk = t >> 2;
    const int mq = t & 3;
    const int k  = b * 64 + kk;
    const float ck = cloc[kk];

    #pragma unroll
    for (int j4 = 0; j4 < 8; ++j4) {
        f32x4 t0 = *(const f32x4*)(Tpart + (size_t)k * FH + mq * 32 + j4 * 4);
        f32x4 t1 = *(const f32x4*)(Tpart + ((size_t)NN + k) * FH + mq * 32 + j4 * 4);
        f32x4 bv = *(const f32x4*)(b1 + mq * 32 + j4 * 4);
        #pragma unroll
        for (int e = 0; e < 4; ++e) {
            float h = t0[e] + t1[e] + bv[e];
            h = h > 0.f ? h : 0.f;
            atomicAdd(&vp[mq * 32 + j4 * 4 + e], ck * h);
        }
    }
    __syncthreads();
    if (t < FH) atomicAdd(&v[t], vp[t]);
}

// ---------------------------------------------------------------------------
// Kernel 4: pooled = v @ W2 + N*b2 ; out = pooled @ W_out + b_out
// ---------------------------------------------------------------------------
__global__ void k4_out(const float* __restrict__ v, const float* __restrict__ W2,
                       const float* __restrict__ b2, const float* __restrict__ Wout,
                       const float* __restrict__ bout, float* __restrict__ out) {
    const int j = threadIdx.x;  // 64
    float pj = (float)NN * b2[j];
    for (int mm = 0; mm < FH; ++mm) pj += v[mm] * W2[mm * FO + j];
    float s = pj * Wout[j];
    #pragma unroll
    for (int off = 32; off; off >>= 1) s += __shfl_down(s, off);
    if (j == 0) out[0] = s + bout[0];
}

// ---------------------------------------------------------------------------
extern "C" void kernel_launch(void* const* d_in, const int* in_sizes, int n_in,
                              void* d_out, int out_size, void* d_ws, size_t ws_size,
                              hipStream_t stream) {
    const float* x    = (const float*)d_in[0];
    const float* adj  = (const float*)d_in[1];
    const float* W1   = (const float*)d_in[2];
    const float* b1   = (const float*)d_in[3];
    const float* W2   = (const float*)d_in[4];
    const float* b2   = (const float*)d_in[5];
    const float* Wout = (const float*)d_in[6];
    const float* bout = (const float*)d_in[7];
    float* out = (float*)d_out;

    char* ws = (char*)d_ws;
    unsigned short* S1T = (unsigned short*)ws;                 // 4 MiB bf16 [128][16384]
    float* Tpart = (float*)(ws + (4u  << 20));                 // 16 MiB fp32 [2][16384][128]
    float* cpart = (float*)(ws + (20u << 20));                 // 64 MiB fp32 [1024][16384]
    float* v     = (float*)(ws + (84u << 20));                 // 512 B fp32 [128]

    hipMemsetAsync(v, 0, 512, stream);                         // zero v only

    k1_s1t<<<256, 256, 0, stream>>>(x, W1, S1T);
    k2_agg<<<512, 256, 0, stream>>>(adj, S1T, Tpart, cpart);
    k3_v  <<<256, 256, 0, stream>>>(Tpart, cpart, b1, v);
    k4_out<<<1, 64, 0, stream>>>(v, W2, b2, Wout, bout, out);
}

// Round 5
// 1596.437 us; speedup vs baseline: 1.1491x; 1.1491x over previous
//
#include <hip/hip_runtime.h>
#include <hip/hip_bf16.h>
#include <stdint.h>

// Problem constants
#define NN   16384   // nodes
#define FI   128     // in feats
#define FH   128     // hidden
#define FO   64      // out feats

// Kernel-2 tiling: BM=16 rows/block, 1024 blocks -> 4 blocks/CU (16 waves/CU)
#define BM   16
#define BK   64
#define NT   (NN / BK)   // 256 K-tiles
#define NBLK (NN / BM)   // 1024 blocks
#define NPART NBLK       // colsum partial rows (one per block)

typedef float f32x4 __attribute__((ext_vector_type(4)));
typedef short s16x8 __attribute__((ext_vector_type(8)));
typedef short s16x4 __attribute__((ext_vector_type(4)));

__device__ __forceinline__ unsigned short f2bf(float f) {
    union { float f; unsigned u; } v; v.f = f;
    unsigned u = v.u;
    return (unsigned short)((u + 0x7FFFu + ((u >> 16) & 1u)) >> 16);  // RNE
}

// async global->LDS DMA, 16 B per lane, linear dest (base + lane*16)
__device__ __forceinline__ void gl_lds16(const unsigned short* g, unsigned short* l) {
    __builtin_amdgcn_global_load_lds(
        (const __attribute__((address_space(1))) void*)g,
        (__attribute__((address_space(3))) void*)l, 16, 0, 0);
}

// ---------------------------------------------------------------------------
// Kernel 1: S1T[n][k] = sum_f x[k][f] * W1[f][n], stored bf16 TRANSPOSED
// (n-major) so kernel 2 can stage B with contiguous 16 B chunks.
// ---------------------------------------------------------------------------
__global__ __launch_bounds__(256) void k1_s1t(const float* __restrict__ x,
                                              const float* __restrict__ W1,
                                              unsigned short* __restrict__ S1T) {
    __shared__ float w1s[FI][FH];     // [f][n], 64 KB, reads are wave-uniform (broadcast)
    __shared__ float xs[64][132];     // 64 k-rows, pad 132 -> uniform 8-way b128 (optimal)

    const int t  = threadIdx.x;
    const int b  = blockIdx.x;        // 256 blocks
    const int k0 = b * 64;

    float* wflat = &w1s[0][0];
    for (int i = t; i < FI * FH; i += 256) wflat[i] = W1[i];

    #pragma unroll
    for (int s = 0; s < 8; ++s) {
        int idx = t + 256 * s;              // 2048 float4 chunks
        int r   = idx >> 5;                 // 0..63
        int f4  = idx & 31;
        f32x4 vv = *(const f32x4*)(x + (size_t)(k0 + r) * FI + f4 * 4);
        *(f32x4*)(&xs[r][f4 * 4]) = vv;
    }
    __syncthreads();

    const int w = t >> 6;                   // wave = n-group (32 cols)
    const int l = t & 63;                   // lane = k-row

    float acc[32];
    #pragma unroll
    for (int j = 0; j < 32; ++j) acc[j] = 0.f;

    for (int f4 = 0; f4 < 32; ++f4) {
        f32x4 xv = *(const f32x4*)(&xs[l][f4 * 4]);
        #pragma unroll
        for (int e = 0; e < 4; ++e) {
            const int f = f4 * 4 + e;
            #pragma unroll
            for (int cth = 0; cth < 8; ++cth) {
                f32x4 wv = *(const f32x4*)(&w1s[f][w * 32 + cth * 4]);  // broadcast
                acc[cth * 4 + 0] += xv[e] * wv[0];
                acc[cth * 4 + 1] += xv[e] * wv[1];
                acc[cth * 4 + 2] += xv[e] * wv[2];
                acc[cth * 4 + 3] += xv[e] * wv[3];
            }
        }
    }

    const int k = k0 + l;
    #pragma unroll
    for (int j = 0; j < 32; ++j) {
        const int n = w * 32 + j;
        S1T[(size_t)n * NN + k] = f2bf(acc[j]);   // lanes -> consecutive k, coalesced
    }
}

// ---------------------------------------------------------------------------
// Kernel 2 (v5): T = adj @ S1, MFMA 16x16x32 bf16.
//
// - B tile (16 KB/tile, S1T bf16) staged via global_load_lds width=16:
//   fire-and-forget DMA, no VGPR round-trip.  LDS linear [128][64]; the
//   16-way bank conflict on fragment ds_read_b128 (128 B row stride) is
//   fixed by XOR-swizzle applied on BOTH sides: pre-swizzled GLOBAL source
//   (src col = 8*((l&7)^(l>>3)) per 8-row chunk) + swizzled read addr
//   (^ ((m&7)<<4)).  LDS dest stays linear as the DMA requires.
// - A tile reg-staged (1 f32x4/thread): colsum shfl partial + fp32->bf16
//   convert + ds_write to padded [16][72] (conflict-free frag reads).
// - BM=16, 1024 blocks, 39 KB LDS -> 4 blocks/CU = 16 waves/CU.
// - One counted s_waitcnt vmcnt(1) + lgkmcnt(0) + raw s_barrier per tile:
//   next tile's loads get the whole MFMA phase in flight, never drained to 0.
// ---------------------------------------------------------------------------
__global__ __launch_bounds__(256, 4) void k2_agg(const float* __restrict__ adj,
                                                 const unsigned short* __restrict__ S1T,
                                                 float* __restrict__ T,
                                                 float* __restrict__ cpart) {
    __shared__ __attribute__((aligned(16))) unsigned short aA[2][BM][72];    //  4,608 B
    __shared__ __attribute__((aligned(16))) unsigned short bB[2][FH][BK];    // 32,768 B
    __shared__ __attribute__((aligned(16))) float cs[2][4][BK];              //  2,048 B

    const int  t    = threadIdx.x;
    const long m0   = (long)blockIdx.x * BM;
    const int  w    = t >> 6;
    const int  l    = t & 63;
    const int  arow = t >> 4;       // A-stage row 0..15
    const int  ac4  = t & 15;       // A-stage float4-col
    const int  m    = l & 15;
    const int  quad = l >> 4;

    // B-stage addressing: instr j (0..3) covers rows w*32 + j*8 .. +8.
    // lane l -> row offset l>>3, pre-swizzled source col 8*((l&7)^(l>>3)).
    const int brow = w * 32 + (l >> 3);
    const int bcol = 8 * ((l & 7) ^ (l >> 3));

    f32x4 acc[2];
    acc[0] = (f32x4){0.f, 0.f, 0.f, 0.f};
    acc[1] = (f32x4){0.f, 0.f, 0.f, 0.f};

    f32x4 pa;   // adj prefetch register (single, reused; issue-use 1 iter apart)

#define LOADA(KT)                                                                 \
    pa = *(const f32x4*)(adj + (m0 + arow) * NN + (long)(KT) * BK + ac4 * 4)

#define STAGEB(SB, KT) do {                                                       \
    const size_t ko_ = (size_t)(KT) * BK;                                         \
    _Pragma("unroll")                                                             \
    for (int j_ = 0; j_ < 4; ++j_)                                                \
        gl_lds16(S1T + (size_t)(brow + j_ * 8) * NN + ko_ + bcol,                 \
                 &bB[SB][w * 32 + j_ * 8][0]);                                    \
} while (0)

#define STAGEA(SB) do {                                                           \
    /* colsum partial: wave's 4 rows (lanes xor 16/32 share ac4) */               \
    f32x4 pv_;                                                                    \
    _Pragma("unroll")                                                             \
    for (int j_ = 0; j_ < 4; ++j_) {                                              \
        float p_ = pa[j_];                                                        \
        p_ += __shfl_xor(p_, 16);                                                 \
        p_ += __shfl_xor(p_, 32);                                                 \
        pv_[j_] = p_;                                                             \
    }                                                                             \
    if (l < 16) *(f32x4*)(&cs[SB][w][l * 4]) = pv_;                               \
    s16x4 q_;                                                                     \
    _Pragma("unroll")                                                             \
    for (int j_ = 0; j_ < 4; ++j_) q_[j_] = (short)f2bf(pa[j_]);                  \
    *(s16x4*)(&aA[SB][arow][ac4 * 4]) = q_;                                       \
} while (0)

// cross-wave colsum combine + one coalesced 256 B store (wave 0)
#define FLUSH(SB, KT) do {                                                        \
    if (t < BK)                                                                   \
        cpart[(size_t)blockIdx.x * NN + (size_t)(KT) * BK + t] =                  \
            cs[SB][0][t] + cs[SB][1][t] + cs[SB][2][t] + cs[SB][3][t];            \
} while (0)

#define COMPUTE(SB) do {                                                          \
    _Pragma("unroll")                                                             \
    for (int ks = 0; ks < 2; ++ks) {                                              \
        s16x8 af_ = *(const s16x8*)((const char*)&aA[SB][m][0] +                  \
                                    ks * 64 + quad * 16);                         \
        _Pragma("unroll")                                                         \
        for (int nt = 0; nt < 2; ++nt) {                                          \
            const int row_ = w * 32 + nt * 16 + m;                                \
            s16x8 bf_ = *(const s16x8*)((const char*)&bB[SB][row_][0] +           \
                          ((ks * 64 + quad * 16) ^ ((m & 7) << 4)));              \
            acc[nt] = __builtin_amdgcn_mfma_f32_16x16x32_bf16(                    \
                af_, bf_, acc[nt], 0, 0, 0);                                      \
        }                                                                         \
    }                                                                             \
} while (0)

    // ---- prologue: tile 0 fully staged; adj for tile 1 in flight ----
    LOADA(0);
    STAGEB(0, 0);
    STAGEA(0);                     // compiler auto-waits vmcnt for pa
    LOADA(1);
    asm volatile("s_waitcnt vmcnt(1) lgkmcnt(0)" ::: "memory");   // B0 landed; pa1 in flight
    __builtin_amdgcn_s_barrier();

    for (int kt = 0; kt < NT; ++kt) {
        const int cur = kt & 1;
        if (kt + 1 < NT) {
            STAGEB(cur ^ 1, kt + 1);          // async DMA, flies across this phase
            STAGEA(cur ^ 1);                  // uses pa (loaded last iter, retired)
            if (kt + 2 < NT) LOADA(kt + 2);   // adj prefetch for next STAGEA
        }
        FLUSH(cur, kt);                       // cs written last iter
        COMPUTE(cur);
        // retire everything except the newest (cpart store); next tile ready
        asm volatile("s_waitcnt vmcnt(1) lgkmcnt(0)" ::: "memory");
        __builtin_amdgcn_s_barrier();
    }

#undef LOADA
#undef STAGEB
#undef STAGEA
#undef FLUSH
#undef COMPUTE

    // epilogue: C/D layout col=lane&15, row=quad*4+reg
    #pragma unroll
    for (int nt = 0; nt < 2; ++nt) {
        const int col = w * 32 + nt * 16 + m;
        #pragma unroll
        for (int r = 0; r < 4; ++r) {
            const long row = m0 + quad * 4 + r;
            T[row * FH + col] = acc[nt][r];
        }
    }
}

// ---------------------------------------------------------------------------
// Kernel 3: finish colsum c[k] = sum_p cpart[p][k] (1024 partials, coalesced),
// then v[m] = sum_k c[k] * relu(T[k][m] + b1[m])
// ---------------------------------------------------------------------------
__global__ __launch_bounds__(256) void k3_v(const float* __restrict__ T,
                                            const float* __restrict__ cpart,
                                            const float* __restrict__ b1,
                                            float* __restrict__ v) {
    __shared__ float vp[FH];
    __shared__ float cw[4][64];
    __shared__ float cloc[64];

    const int t = threadIdx.x;
    const int b = blockIdx.x;      // 256 blocks x 64 rows
    const int w = t >> 6;
    const int l = t & 63;

    // 1024-way partial reduction for this block's 64 k-rows.
    float s = 0.f;
    #pragma unroll 8
    for (int i = 0; i < NPART / 4; ++i)
        s += cpart[(size_t)(w + 4 * i) * NN + b * 64 + l];
    cw[w][l] = s;
    if (t < FH) vp[t] = 0.f;
    __syncthreads();
    if (t < 64) cloc[t] = cw[0][t] + cw[1][t] + cw[2][t] + cw[3][t];
    __syncthreads();

    const int kk = t >> 2;
    const int mq = t & 3;
    const int k  = b * 64 + kk;
    const float ck = cloc[kk];

    #pragma unroll
    for (int j4 = 0; j4 < 8; ++j4) {
        f32x4 tv = *(const f32x4*)(T + (size_t)k * FH + mq * 32 + j4 * 4);
        f32x4 bv = *(const f32x4*)(b1 + mq * 32 + j4 * 4);
        #pragma unroll
        for (int e = 0; e < 4; ++e) {
            float h = tv[e] + bv[e];
            h = h > 0.f ? h : 0.f;
            atomicAdd(&vp[mq * 32 + j4 * 4 + e], ck * h);
        }
    }
    __syncthreads();
    if (t < FH) atomicAdd(&v[t], vp[t]);
}

// ---------------------------------------------------------------------------
// Kernel 4: pooled = v @ W2 + N*b2 ; out = pooled @ W_out + b_out
// ---------------------------------------------------------------------------
__global__ void k4_out(const float* __restrict__ v, const float* __restrict__ W2,
                       const float* __restrict__ b2, const float* __restrict__ Wout,
                       const float* __restrict__ bout, float* __restrict__ out) {
    const int j = threadIdx.x;  // 64
    float pj = (float)NN * b2[j];
    for (int mm = 0; mm < FH; ++mm) pj += v[mm] * W2[mm * FO + j];
    float s = pj * Wout[j];
    #pragma unroll
    for (int off = 32; off; off >>= 1) s += __shfl_down(s, off);
    if (j == 0) out[0] = s + bout[0];
}

// ---------------------------------------------------------------------------
extern "C" void kernel_launch(void* const* d_in, const int* in_sizes, int n_in,
                              void* d_out, int out_size, void* d_ws, size_t ws_size,
                              hipStream_t stream) {
    const float* x    = (const float*)d_in[0];
    const float* adj  = (const float*)d_in[1];
    const float* W1   = (const float*)d_in[2];
    const float* b1   = (const float*)d_in[3];
    const float* W2   = (const float*)d_in[4];
    const float* b2   = (const float*)d_in[5];
    const float* Wout = (const float*)d_in[6];
    const float* bout = (const float*)d_in[7];
    float* out = (float*)d_out;

    char* ws = (char*)d_ws;
    unsigned short* S1T = (unsigned short*)ws;                 // 4 MiB bf16 [128][16384]
    float* T     = (float*)(ws + (4u  << 20));                 // 8 MiB fp32 [16384][128]
    float* cpart = (float*)(ws + (12u << 20));                 // 64 MiB fp32 [1024][16384]
    float* v     = (float*)(ws + (76u << 20));                 // 512 B fp32 [128]

    hipMemsetAsync(v, 0, 512, stream);                         // zero v only

    k1_s1t<<<256, 256, 0, stream>>>(x, W1, S1T);
    k2_agg<<<NBLK, 256, 0, stream>>>(adj, S1T, T, cpart);
    k3_v  <<<256, 256, 0, stream>>>(T, cpart, b1, v);
    k4_out<<<1, 64, 0, stream>>>(v, W2, b2, Wout, bout, out);
}

// Round 6
// 1487.315 us; speedup vs baseline: 1.2335x; 1.0734x over previous
//
#include <hip/hip_runtime.h>
#include <hip/hip_bf16.h>
#include <stdint.h>

// Problem constants
#define NN   16384   // nodes
#define FI   128     // in feats
#define FH   128     // hidden
#define FO   64      // out feats

// Kernel-2 tiling: BM=32 rows/block, K split in half -> 1024 blocks = 4/CU.
#define BM   32
#define BK   64
#define LDK  72          // padded bf16 leading dim (b128 reads at the 8-clk floor)
#define KHALF (NN / 2)
#define NTH  (KHALF / BK)   // 128 K-tiles per block
#define NPART 512           // colsum partial rows (one per rb; kh halves share a row)

typedef float f32x4 __attribute__((ext_vector_type(4)));
typedef short s16x8 __attribute__((ext_vector_type(8)));
typedef short s16x4 __attribute__((ext_vector_type(4)));

__device__ __forceinline__ unsigned short f2bf(float f) {
    union { float f; unsigned u; } v; v.f = f;
    unsigned u = v.u;
    return (unsigned short)((u + 0x7FFFu + ((u >> 16) & 1u)) >> 16);  // RNE
}

// ---------------------------------------------------------------------------
// Kernel 1: S1T[n][k] = sum_f x[k][f] * W1[f][n], stored bf16 TRANSPOSED
// (n-major) so kernel 2 can read B-fragments with contiguous 16 B loads.
// ---------------------------------------------------------------------------
__global__ __launch_bounds__(256) void k1_s1t(const float* __restrict__ x,
                                              const float* __restrict__ W1,
                                              unsigned short* __restrict__ S1T) {
    __shared__ float w1s[FI][FH];     // [f][n], 64 KB, reads are wave-uniform (broadcast)
    __shared__ float xs[64][132];     // 64 k-rows, pad 132 -> uniform 8-way b128 (optimal)

    const int t  = threadIdx.x;
    const int b  = blockIdx.x;        // 256 blocks
    const int k0 = b * 64;

    float* wflat = &w1s[0][0];
    for (int i = t; i < FI * FH; i += 256) wflat[i] = W1[i];

    #pragma unroll
    for (int s = 0; s < 8; ++s) {
        int idx = t + 256 * s;              // 2048 float4 chunks
        int r   = idx >> 5;                 // 0..63
        int f4  = idx & 31;
        f32x4 vv = *(const f32x4*)(x + (size_t)(k0 + r) * FI + f4 * 4);
        *(f32x4*)(&xs[r][f4 * 4]) = vv;
    }
    __syncthreads();

    const int w = t >> 6;                   // wave = n-group (32 cols)
    const int l = t & 63;                   // lane = k-row

    float acc[32];
    #pragma unroll
    for (int j = 0; j < 32; ++j) acc[j] = 0.f;

    for (int f4 = 0; f4 < 32; ++f4) {
        f32x4 xv = *(const f32x4*)(&xs[l][f4 * 4]);
        #pragma unroll
        for (int e = 0; e < 4; ++e) {
            const int f = f4 * 4 + e;
            #pragma unroll
            for (int cth = 0; cth < 8; ++cth) {
                f32x4 wv = *(const f32x4*)(&w1s[f][w * 32 + cth * 4]);  // broadcast
                acc[cth * 4 + 0] += xv[e] * wv[0];
                acc[cth * 4 + 1] += xv[e] * wv[1];
                acc[cth * 4 + 2] += xv[e] * wv[2];
                acc[cth * 4 + 3] += xv[e] * wv[3];
            }
        }
    }

    const int k = k0 + l;
    #pragma unroll
    for (int j = 0; j < 32; ++j) {
        const int n = w * 32 + j;
        S1T[(size_t)n * NN + k] = f2bf(acc[j]);   // lanes -> consecutive k, coalesced
    }
}

// ---------------------------------------------------------------------------
// Kernel 2 (v6): T = adj @ S1, MFMA 16x16x32 bf16.
//
// R1's proven structure (reg-staged A+B, 2-tile-deep X/Y prefetch sets,
// padded LDK=72 tiles) with the occupancy fix: K-split 2 -> 1024 blocks =
// 4 blocks/CU, single-buffered B + double-buffered A shrinks LDS to 28.7 KB,
// __launch_bounds__(256,4) keeps VGPR<=128 -> 16 waves/CU (2x R1's TLP).
// Raw s_barrier + lgkmcnt(0) only, so X/Y global loads (issued a full tile
// ahead) stay in flight across barriers.  2 barriers/tile x 128 tiles =
// same barrier count as R1.  Outputs: Tpart[kh] slabs + cpart[512][NN]
// (kh halves write disjoint column ranges of the same cpart row).
// ---------------------------------------------------------------------------
__global__ __launch_bounds__(256, 4) void k2_agg(const float* __restrict__ adj,
                                                 const unsigned short* __restrict__ S1T,
                                                 float* __restrict__ Tpart,
                                                 float* __restrict__ cpart) {
    __shared__ unsigned short aA[2][BM][LDK];   //  9,216 B (double)
    __shared__ unsigned short bBs[FH][LDK];     // 18,432 B (single)
    __shared__ float cs[4][BK];                 //  1,024 B

    const int  t    = threadIdx.x;
    const int  rb   = blockIdx.x >> 1;          // row-block 0..511
    const int  kh   = blockIdx.x & 1;           // k-half
    const long m0   = (long)rb * BM;
    const long k0   = (long)kh * KHALF;
    const int  w    = t >> 6;
    const int  l    = t & 63;
    const int  ar   = t >> 4;       // adj stage row 0..15 (+16)
    const int  ac4  = t & 15;       // adj stage float4-col
    const int  sn   = t >> 3;       // s1 stage row 0..31 (+32s)
    const int  sch  = t & 7;        // s1 stage 16B chunk
    const int  m    = l & 15;
    const int  quad = l >> 4;

    f32x4 acc[2][2];
    #pragma unroll
    for (int i = 0; i < 2; ++i)
        #pragma unroll
        for (int j = 0; j < 2; ++j) acc[i][j] = (f32x4){0.f, 0.f, 0.f, 0.f};

    // two named prefetch sets, each holds one K-tile of A (2 f32x4) + B (4 s16x8)
    f32x4 paX0, paX1, paY0, paY1;
    s16x8 psX[4], psY[4];

#define BAR() do {                                                                \
    asm volatile("s_waitcnt lgkmcnt(0)" ::: "memory");                            \
    __builtin_amdgcn_s_barrier();                                                 \
} while (0)

#define LOAD(PA0, PA1, PS, J) do {                                                \
    const long koff_ = k0 + (long)(J) * BK;                                       \
    PA0 = *(const f32x4*)(adj + (m0 + ar) * NN + koff_ + ac4 * 4);                \
    PA1 = *(const f32x4*)(adj + (m0 + ar + 16) * NN + koff_ + ac4 * 4);           \
    _Pragma("unroll")                                                             \
    for (int s_ = 0; s_ < 4; ++s_)                                                \
        PS[s_] = *(const s16x8*)(S1T + (size_t)(sn + 32 * s_) * NN + koff_ + sch * 8); \
} while (0)

// colsum partial + cvt + A-tile LDS write (consumes PA regs)
#define CSUM_STAGEA(SB, PA0, PA1) do {                                            \
    f32x4 pv_;                                                                    \
    _Pragma("unroll")                                                             \
    for (int j_ = 0; j_ < 4; ++j_) {                                              \
        float p_ = PA0[j_] + PA1[j_];                                             \
        p_ += __shfl_xor(p_, 16);                                                 \
        p_ += __shfl_xor(p_, 32);                                                 \
        pv_[j_] = p_;                                                             \
    }                                                                             \
    if (l < 16) *(f32x4*)(&cs[w][l * 4]) = pv_;                                   \
    s16x4 q0_, q1_;                                                               \
    _Pragma("unroll")                                                             \
    for (int j_ = 0; j_ < 4; ++j_) {                                              \
        q0_[j_] = (short)f2bf(PA0[j_]);                                           \
        q1_[j_] = (short)f2bf(PA1[j_]);                                           \
    }                                                                             \
    *(s16x4*)(&aA[SB][ar][ac4 * 4])      = q0_;                                   \
    *(s16x4*)(&aA[SB][ar + 16][ac4 * 4]) = q1_;                                   \
} while (0)

#define STAGEB(PS) do {                                                           \
    _Pragma("unroll")                                                             \
    for (int s_ = 0; s_ < 4; ++s_)                                                \
        *(s16x8*)(&bBs[sn + 32 * s_][sch * 8]) = PS[s_];                          \
} while (0)

// cross-wave colsum combine + one coalesced 256 B store (wave 0)
#define FLUSH(J) do {                                                             \
    if (t < BK)                                                                   \
        cpart[(size_t)rb * NN + k0 + (long)(J) * BK + t] =                        \
            cs[0][t] + cs[1][t] + cs[2][t] + cs[3][t];                            \
} while (0)

#define COMPUTE(SB) do {                                                          \
    _Pragma("unroll")                                                             \
    for (int ks = 0; ks < 2; ++ks) {                                              \
        s16x8 af_[2], bf_[2];                                                     \
        _Pragma("unroll")                                                         \
        for (int mt = 0; mt < 2; ++mt)                                            \
            af_[mt] = *(const s16x8*)(&aA[SB][mt * 16 + m][ks * 32 + quad * 8]);  \
        _Pragma("unroll")                                                         \
        for (int nt = 0; nt < 2; ++nt)                                            \
            bf_[nt] = *(const s16x8*)(&bBs[w * 32 + nt * 16 + m][ks * 32 + quad * 8]); \
        _Pragma("unroll")                                                         \
        for (int mt = 0; mt < 2; ++mt)                                            \
            _Pragma("unroll")                                                     \
            for (int nt = 0; nt < 2; ++nt)                                        \
                acc[mt][nt] = __builtin_amdgcn_mfma_f32_16x16x32_bf16(            \
                    af_[mt], bf_[nt], acc[mt][nt], 0, 0, 0);                      \
    }                                                                             \
} while (0)

    // ---- prologue: tile 0 staged, tile 1 in regs ----
    LOAD(paX0, paX1, psX, 0);
    LOAD(paY0, paY1, psY, 1);
    CSUM_STAGEA(0, paX0, paX1);
    STAGEB(psX);
    BAR();
    FLUSH(0);
    BAR();

    for (int j = 0; j < NTH; j += 2) {
        // ---- tile j (even): aA[0] + bBs hold tile j ----
        if (j + 2 < NTH) LOAD(paX0, paX1, psX, j + 2);   // X free since prev pair
        COMPUTE(0);
        CSUM_STAGEA(1, paY0, paY1);                      // tile j+1 A + colsum
        BAR();                                           // all waves done with bBs(j), cs ready
        STAGEB(psY);                                     // tile j+1 B
        FLUSH(j + 1);
        BAR();                                           // bBs(j+1) visible, cs free

        // ---- tile j+1 (odd): aA[1] + bBs hold tile j+1 ----
        if (j + 3 < NTH) LOAD(paY0, paY1, psY, j + 3);
        COMPUTE(1);
        if (j + 2 < NTH) CSUM_STAGEA(0, paX0, paX1);     // tile j+2 A + colsum
        BAR();
        if (j + 2 < NTH) {
            STAGEB(psX);                                 // tile j+2 B
            FLUSH(j + 2);
        }
        BAR();
    }

#undef BAR
#undef LOAD
#undef CSUM_STAGEA
#undef STAGEB
#undef FLUSH
#undef COMPUTE

    // epilogue: C/D layout col=lane&15, row=quad*4+reg; this k-half's slab
    float* Tp = Tpart + (size_t)kh * NN * FH;
    #pragma unroll
    for (int mt = 0; mt < 2; ++mt)
        #pragma unroll
        for (int nt = 0; nt < 2; ++nt) {
            const int col = w * 32 + nt * 16 + m;
            #pragma unroll
            for (int r = 0; r < 4; ++r) {
                const long row = m0 + mt * 16 + quad * 4 + r;
                Tp[row * FH + col] = acc[mt][nt][r];
            }
        }
}

// ---------------------------------------------------------------------------
// Kernel 3: finish colsum c[k] = sum_p cpart[p][k] (512 partials, coalesced),
// then v[m] = sum_k c[k] * relu(Tpart0[k][m] + Tpart1[k][m] + b1[m])
// ---------------------------------------------------------------------------
__global__ __launch_bounds__(256) void k3_v(const float* __restrict__ Tpart,
                                            const float* __restrict__ cpart,
                                            const float* __restrict__ b1,
                                            float* __restrict__ v) {
    __shared__ float vp[FH];
    __shared__ float cw[4][64];
    __shared__ float cloc[64];

    const int t = threadIdx.x;
    const int b = blockIdx.x;      // 256 blocks x 64 rows
    const int w = t >> 6;
    const int l = t & 63;

    // 512-way partial reduction for this block's 64 k-rows.
    float s = 0.f;
    #pragma unroll 8
    for (int i = 0; i < NPART / 4; ++i)
        s += cpart[(size_t)(w + 4 * i) * NN + b * 64 + l];
    cw[w][l] = s;
    if (t < FH) vp[t] = 0.f;
    __syncthreads();
    if (t < 64) cloc[t] = cw[0][t] + cw[1][t] + cw[2][t] + cw[3][t];
    __syncthreads();

    const int kk = t >> 2;
    const int mq = t & 3;
    const int k  = b * 64 + kk;
    const float ck = cloc[kk];

    #pragma unroll
    for (int j4 = 0; j4 < 8; ++j4) {
        f32x4 t0 = *(const f32x4*)(Tpart + (size_t)k * FH + mq * 32 + j4 * 4);
        f32x4 t1 = *(const f32x4*)(Tpart + ((size_t)NN + k) * FH + mq * 32 + j4 * 4);
        f32x4 bv = *(const f32x4*)(b1 + mq * 32 + j4 * 4);
        #pragma unroll
        for (int e = 0; e < 4; ++e) {
            float h = t0[e] + t1[e] + bv[e];
            h = h > 0.f ? h : 0.f;
            atomicAdd(&vp[mq * 32 + j4 * 4 + e], ck * h);
        }
    }
    __syncthreads();
    if (t < FH) atomicAdd(&v[t], vp[t]);
}

// ---------------------------------------------------------------------------
// Kernel 4: pooled = v @ W2 + N*b2 ; out = pooled @ W_out + b_out
// ---------------------------------------------------------------------------
__global__ void k4_out(const float* __restrict__ v, const float* __restrict__ W2,
                       const float* __restrict__ b2, const float* __restrict__ Wout,
                       const float* __restrict__ bout, float* __restrict__ out) {
    const int j = threadIdx.x;  // 64
    float pj = (float)NN * b2[j];
    for (int mm = 0; mm < FH; ++mm) pj += v[mm] * W2[mm * FO + j];
    float s = pj * Wout[j];
    #pragma unroll
    for (int off = 32; off; off >>= 1) s += __shfl_down(s, off);
    if (j == 0) out[0] = s + bout[0];
}

// ---------------------------------------------------------------------------
extern "C" void kernel_launch(void* const* d_in, const int* in_sizes, int n_in,
                              void* d_out, int out_size, void* d_ws, size_t ws_size,
                              hipStream_t stream) {
    const float* x    = (const float*)d_in[0];
    const float* adj  = (const float*)d_in[1];
    const float* W1   = (const float*)d_in[2];
    const float* b1   = (const float*)d_in[3];
    const float* W2   = (const float*)d_in[4];
    const float* b2   = (const float*)d_in[5];
    const float* Wout = (const float*)d_in[6];
    const float* bout = (const float*)d_in[7];
    float* out = (float*)d_out;

    char* ws = (char*)d_ws;
    unsigned short* S1T = (unsigned short*)ws;                 // 4 MiB bf16 [128][16384]
    float* Tpart = (float*)(ws + (4u  << 20));                 // 16 MiB fp32 [2][16384][128]
    float* cpart = (float*)(ws + (20u << 20));                 // 32 MiB fp32 [512][16384]
    float* v     = (float*)(ws + (52u << 20));                 // 512 B fp32 [128]

    hipMemsetAsync(v, 0, 512, stream);                         // zero v only

    k1_s1t<<<256, 256, 0, stream>>>(x, W1, S1T);
    k2_agg<<<1024, 256, 0, stream>>>(adj, S1T, Tpart, cpart);
    k3_v  <<<256, 256, 0, stream>>>(Tpart, cpart, b1, v);
    k4_out<<<1, 64, 0, stream>>>(v, W2, b2, Wout, bout, out);
}